// Round 1
// baseline (2039.195 us; speedup 1.0000x reference)
//
#include <hip/hip_runtime.h>
#include <hip/hip_bf16.h>
#include <math.h>

// MHA forward, fp32 baseline.
// B=4, S=2048, D_MODEL=1024, H=16, DK=64.
// Pipeline: 3x gemm_nt (Q,K,V proj, scatter to [B,H,S,DK]) -> flash attn -> gemm_nt (out proj).

#define D_MODEL 1024
#define NHEAD   16
#define DK      64
#define BATCH   4
#define SEQ     2048
#define MROWS   (BATCH * SEQ)   // 8192

// ---------------- GEMM: C[M,N] = A[M,K] @ W[N,K]^T + bias[N] ----------------
constexpr int BM = 128, BN = 128, BKK = 16;

// LAYOUT 0: C row-major [M, N].
// LAYOUT 1: scatter col n = h*64+d, row m = b*SEQ+s  ->  C[((b*H+h)*SEQ+s)*DK + d]
template <int LAYOUT>
__global__ __launch_bounds__(256) void gemm_nt(const float* __restrict__ A,
                                               const float* __restrict__ W,
                                               const float* __restrict__ bias,
                                               float* __restrict__ C,
                                               int M, int N, int K) {
  __shared__ float As[BKK][BM + 4];  // [k][m], stride 132
  __shared__ float Bs[BKK][BN + 4];  // [k][n]
  const int t = threadIdx.x;
  const int tx = t & 15, ty = t >> 4;
  const int n0 = blockIdx.x * BN, m0 = blockIdx.y * BM;

  float acc[8][8] = {};

  for (int k0 = 0; k0 < K; k0 += BKK) {
    __syncthreads();
    // Stage A-tile (128x16) and W-tile (128x16), transposed into LDS.
    // 512 float4 per tile; thread t loads float4 f = 2t, 2t+1 of each.
#pragma unroll
    for (int p = 0; p < 2; ++p) {
      const int f = t * 2 + p;
      const int row = f >> 2, kq = (f & 3) << 2;
      const float4 av = *reinterpret_cast<const float4*>(&A[(size_t)(m0 + row) * K + k0 + kq]);
      As[kq + 0][row] = av.x; As[kq + 1][row] = av.y;
      As[kq + 2][row] = av.z; As[kq + 3][row] = av.w;
      const float4 wv = *reinterpret_cast<const float4*>(&W[(size_t)(n0 + row) * K + k0 + kq]);
      Bs[kq + 0][row] = wv.x; Bs[kq + 1][row] = wv.y;
      Bs[kq + 2][row] = wv.z; Bs[kq + 3][row] = wv.w;
    }
    __syncthreads();

#pragma unroll
    for (int k = 0; k < BKK; ++k) {
      float a[8], b[8];
      *reinterpret_cast<float4*>(&a[0]) = *reinterpret_cast<const float4*>(&As[k][ty * 8]);
      *reinterpret_cast<float4*>(&a[4]) = *reinterpret_cast<const float4*>(&As[k][ty * 8 + 4]);
      *reinterpret_cast<float4*>(&b[0]) = *reinterpret_cast<const float4*>(&Bs[k][tx * 8]);
      *reinterpret_cast<float4*>(&b[4]) = *reinterpret_cast<const float4*>(&Bs[k][tx * 8 + 4]);
#pragma unroll
      for (int i = 0; i < 8; ++i)
#pragma unroll
        for (int j = 0; j < 8; ++j)
          acc[i][j] += a[i] * b[j];
    }
  }

  // Epilogue: bias + store.
#pragma unroll
  for (int i = 0; i < 8; ++i) {
    const int mrow = m0 + ty * 8 + i;
#pragma unroll
    for (int j4 = 0; j4 < 2; ++j4) {
      const int n = n0 + tx * 8 + j4 * 4;
      float4 ov;
      ov.x = acc[i][j4 * 4 + 0] + bias[n + 0];
      ov.y = acc[i][j4 * 4 + 1] + bias[n + 1];
      ov.z = acc[i][j4 * 4 + 2] + bias[n + 2];
      ov.w = acc[i][j4 * 4 + 3] + bias[n + 3];
      if (LAYOUT == 0) {
        *reinterpret_cast<float4*>(&C[(size_t)mrow * N + n]) = ov;
      } else {
        const int b = mrow >> 11, s = mrow & (SEQ - 1);
        const int h = n >> 6, d = n & (DK - 1);
        *reinterpret_cast<float4*>(&C[(((size_t)(b * NHEAD + h) * SEQ) + s) * DK + d]) = ov;
      }
    }
  }
}

// ---------------- Flash attention (fp32) ----------------
// Q,K,V in [B,H,S,DK]. One block = one (b,h) and 64 query rows.
// Block 256 threads = 16x16 grid, 4x4 micro-tiles over the 64x64 score tile.
// Ks buffer ([d][kv]) is reused as Ps ([kv][q]) after scores are consumed.
__global__ __launch_bounds__(256) void attn_kernel(const float* __restrict__ Q,
                                                   const float* __restrict__ K,
                                                   const float* __restrict__ V,
                                                   float* __restrict__ O) {
  __shared__ float Qs[DK][68];   // [d][q]
  __shared__ float Ks[DK][68];   // [d][kv]; later aliased as Ps[kv][q]
  __shared__ float Vs[64][68];   // [kv][d]

  const int t = threadIdx.x;
  const int tx = t & 15, ty = t >> 4;
  const int h = blockIdx.y, b = blockIdx.z;
  const int q0 = blockIdx.x * 64;
  const size_t bh = ((size_t)(b * NHEAD + h)) * SEQ * DK;
  const float* Qp = Q + bh + (size_t)q0 * DK;
  const float* Kp = K + bh;
  const float* Vp = V + bh;

  // Stage Q tile transposed: Qs[d][q].
#pragma unroll
  for (int p = 0; p < 4; ++p) {
    const int f = t + p * 256;          // [0,1024)
    const int r = f >> 4, d4 = (f & 15) << 2;
    const float4 q4 = *reinterpret_cast<const float4*>(&Qp[r * DK + d4]);
    Qs[d4 + 0][r] = q4.x; Qs[d4 + 1][r] = q4.y;
    Qs[d4 + 2][r] = q4.z; Qs[d4 + 3][r] = q4.w;
  }

  float mrow[4], lrow[4], o[4][4];
#pragma unroll
  for (int i = 0; i < 4; ++i) {
    mrow[i] = -INFINITY;
    lrow[i] = 0.f;
#pragma unroll
    for (int j = 0; j < 4; ++j) o[i][j] = 0.f;
  }

  for (int kt = 0; kt < SEQ / 64; ++kt) {
    __syncthreads();  // previous tile's PV reads done
    const float* Kt = Kp + (size_t)kt * 64 * DK;
    const float* Vt = Vp + (size_t)kt * 64 * DK;
#pragma unroll
    for (int p = 0; p < 4; ++p) {
      const int f = t + p * 256;
      const int r = f >> 4, d4 = (f & 15) << 2;
      const float4 k4 = *reinterpret_cast<const float4*>(&Kt[r * DK + d4]);
      Ks[d4 + 0][r] = k4.x; Ks[d4 + 1][r] = k4.y;
      Ks[d4 + 2][r] = k4.z; Ks[d4 + 3][r] = k4.w;
      *reinterpret_cast<float4*>(&Vs[r][d4]) =
          *reinterpret_cast<const float4*>(&Vt[r * DK + d4]);
    }
    __syncthreads();

    // Scores: s[i][j] = sum_d Q[q0+ty*4+i][d] * K[kt*64+tx*4+j][d]
    float s[4][4] = {};
#pragma unroll 8
    for (int d = 0; d < DK; ++d) {
      float qf[4], kf[4];
      *reinterpret_cast<float4*>(qf) = *reinterpret_cast<const float4*>(&Qs[d][ty * 4]);
      *reinterpret_cast<float4*>(kf) = *reinterpret_cast<const float4*>(&Ks[d][tx * 4]);
#pragma unroll
      for (int i = 0; i < 4; ++i)
#pragma unroll
        for (int j = 0; j < 4; ++j)
          s[i][j] += qf[i] * kf[j];
    }

    // Online softmax update (per q-row; reduce across the 16 tx lanes).
#pragma unroll
    for (int i = 0; i < 4; ++i) {
#pragma unroll
      for (int j = 0; j < 4; ++j) s[i][j] *= 0.125f;  // 1/sqrt(64)
      float tm = fmaxf(fmaxf(s[i][0], s[i][1]), fmaxf(s[i][2], s[i][3]));
#pragma unroll
      for (int w = 1; w < 16; w <<= 1) tm = fmaxf(tm, __shfl_xor(tm, w));
      const float mn = fmaxf(mrow[i], tm);
      const float fsc = __expf(mrow[i] - mn);
      float rs = 0.f;
#pragma unroll
      for (int j = 0; j < 4; ++j) {
        s[i][j] = __expf(s[i][j] - mn);
        rs += s[i][j];
      }
#pragma unroll
      for (int w = 1; w < 16; w <<= 1) rs += __shfl_xor(rs, w);
      lrow[i] = lrow[i] * fsc + rs;
      mrow[i] = mn;
#pragma unroll
      for (int j = 0; j < 4; ++j) o[i][j] *= fsc;
    }

    __syncthreads();  // all threads done reading Ks as K
    // Write P transposed into the K buffer: Ps[kv][q]
#pragma unroll
    for (int i = 0; i < 4; ++i)
#pragma unroll
      for (int j = 0; j < 4; ++j)
        Ks[tx * 4 + j][ty * 4 + i] = s[i][j];
    __syncthreads();

    // PV: o[i][j] += sum_kv P[q][kv] * V[kv][d], d = tx*4+j
#pragma unroll 8
    for (int kv = 0; kv < 64; ++kv) {
      float pf[4], vf[4];
      *reinterpret_cast<float4*>(pf) = *reinterpret_cast<const float4*>(&Ks[kv][ty * 4]);
      *reinterpret_cast<float4*>(vf) = *reinterpret_cast<const float4*>(&Vs[kv][tx * 4]);
#pragma unroll
      for (int i = 0; i < 4; ++i)
#pragma unroll
        for (int j = 0; j < 4; ++j)
          o[i][j] += pf[i] * vf[j];
    }
  }

  // Epilogue: normalize and write ctx in [b, s, h*64+d] layout.
#pragma unroll
  for (int i = 0; i < 4; ++i) {
    const float inv = 1.f / lrow[i];
    float4 ov;
    ov.x = o[i][0] * inv; ov.y = o[i][1] * inv;
    ov.z = o[i][2] * inv; ov.w = o[i][3] * inv;
    const size_t srow = (size_t)b * SEQ + q0 + ty * 4 + i;
    *reinterpret_cast<float4*>(&O[srow * D_MODEL + h * DK + tx * 4]) = ov;
  }
}

extern "C" void kernel_launch(void* const* d_in, const int* in_sizes, int n_in,
                              void* d_out, int out_size, void* d_ws, size_t ws_size,
                              hipStream_t stream) {
  const float* query = (const float*)d_in[0];
  const float* key   = (const float*)d_in[1];
  const float* value = (const float*)d_in[2];
  const float* wq = (const float*)d_in[3];
  const float* bq = (const float*)d_in[4];
  const float* wk = (const float*)d_in[5];
  const float* bk = (const float*)d_in[6];
  const float* wv = (const float*)d_in[7];
  const float* bv = (const float*)d_in[8];
  const float* wo = (const float*)d_in[9];
  const float* bo = (const float*)d_in[10];
  float* out = (float*)d_out;

  const size_t tsz = (size_t)MROWS * D_MODEL;  // 8.39M floats per tensor
  float* Qws = (float*)d_ws;
  float* Kws = Qws + tsz;
  float* Vws = Kws + tsz;
  float* Ctx = Vws + tsz;
  // needs ws_size >= 4 * tsz * 4B = 134 MB

  const dim3 gg(D_MODEL / BN, MROWS / BM);  // (8, 64)
  const dim3 gb(256);

  gemm_nt<1><<<gg, gb, 0, stream>>>(query, wq, bq, Qws, MROWS, D_MODEL, D_MODEL);
  gemm_nt<1><<<gg, gb, 0, stream>>>(key,   wk, bk, Kws, MROWS, D_MODEL, D_MODEL);
  gemm_nt<1><<<gg, gb, 0, stream>>>(value, wv, bv, Vws, MROWS, D_MODEL, D_MODEL);

  attn_kernel<<<dim3(SEQ / 64, NHEAD, BATCH), 256, 0, stream>>>(Qws, Kws, Vws, Ctx);

  gemm_nt<0><<<gg, gb, 0, stream>>>(Ctx, wo, bo, out, MROWS, D_MODEL, D_MODEL);
}

// Round 2
// 548.266 us; speedup vs baseline: 3.7194x; 3.7194x over previous
//
#include <hip/hip_runtime.h>
#include <math.h>

#define D_MODEL 1024
#define NHEAD   16
#define DK      64
#define BATCH   4
#define SEQ     2048
#define MROWS   8192

typedef __attribute__((ext_vector_type(4))) float f32x4;
typedef __attribute__((ext_vector_type(8))) short bf16x8;

__device__ __forceinline__ unsigned short f2bf(float f) {
  union { float f; unsigned int u; } x; x.f = f;
  unsigned int r = x.u + 0x7fffu + ((x.u >> 16) & 1u);
  return (unsigned short)(r >> 16);
}

// ---------------- fp32 -> bf16 convert (8 elems/thread) ----------------
__global__ __launch_bounds__(256) void cvt_bf16(const float* __restrict__ in,
                                                unsigned short* __restrict__ out, int n8) {
  const int i = blockIdx.x * blockDim.x + threadIdx.x;
  if (i >= n8) return;
  const float4* p = (const float4*)in + (size_t)i * 2;
  const float4 a = p[0], b = p[1];
  int4 v;
  v.x = f2bf(a.x) | ((int)f2bf(a.y) << 16);
  v.y = f2bf(a.z) | ((int)f2bf(a.w) << 16);
  v.z = f2bf(b.x) | ((int)f2bf(b.y) << 16);
  v.w = f2bf(b.z) | ((int)f2bf(b.w) << 16);
  *(int4*)(out + (size_t)i * 8) = v;
}

// ---------------- bf16 MFMA GEMM: C[M,N] = A[M,K] @ W[N,K]^T + bias ----------------
// m97 structure: 128x128 tile, BK=32, 4 waves each owning a 64x64 quadrant (4x4 frags).
// MODE 0: scatter bf16 to [B,H,S,64], value scaled by `scale` after bias (Q/K proj)
// MODE 1: scatter bf16 to [B,H,64,S] (V proj, transposed for PV fragments)
// MODE 2: fp32 row-major [M,N] (output proj)
template <int MODE>
__global__ __launch_bounds__(256) void gemm_bt(const unsigned short* __restrict__ A,
                                               const unsigned short* __restrict__ W,
                                               const float* __restrict__ bias,
                                               void* __restrict__ Cout, float scale) {
  __shared__ unsigned short Asb[128 * 32];
  __shared__ unsigned short Bsb[128 * 32];
  const int t = threadIdx.x;
  const int lane = t & 63, w = t >> 6;
  const int wr = w >> 1, wc = w & 1;
  const int g = lane >> 4, cl = lane & 15;
  const int m0 = blockIdx.y * 128, n0 = blockIdx.x * 128;

  f32x4 acc[4][4];
#pragma unroll
  for (int i = 0; i < 4; ++i)
#pragma unroll
    for (int j = 0; j < 4; ++j) acc[i][j] = (f32x4){0.f, 0.f, 0.f, 0.f};

  for (int k0 = 0; k0 < D_MODEL; k0 += 32) {
    __syncthreads();  // previous tile's reads complete
#pragma unroll
    for (int p = 0; p < 2; ++p) {
      const int c = p * 256 + t;  // 16B chunk id; row=c>>2, chunk-in-row=c&3
      const unsigned short* ga = A + (size_t)(m0 + (c >> 2)) * D_MODEL + k0 + (c & 3) * 8;
      const unsigned short* gw = W + (size_t)(n0 + (c >> 2)) * D_MODEL + k0 + (c & 3) * 8;
      __builtin_amdgcn_global_load_lds(
          (const __attribute__((address_space(1))) unsigned int*)ga,
          (__attribute__((address_space(3))) unsigned int*)(Asb + (size_t)c * 8), 16, 0, 0);
      __builtin_amdgcn_global_load_lds(
          (const __attribute__((address_space(1))) unsigned int*)gw,
          (__attribute__((address_space(3))) unsigned int*)(Bsb + (size_t)c * 8), 16, 0, 0);
    }
    __syncthreads();  // implies vmcnt(0): staged data visible

    bf16x8 af[4], bfr[4];
#pragma unroll
    for (int mi = 0; mi < 4; ++mi)
      af[mi] = *(const bf16x8*)&Asb[(wr * 64 + mi * 16 + cl) * 32 + g * 8];
#pragma unroll
    for (int ni = 0; ni < 4; ++ni)
      bfr[ni] = *(const bf16x8*)&Bsb[(wc * 64 + ni * 16 + cl) * 32 + g * 8];
#pragma unroll
    for (int mi = 0; mi < 4; ++mi)
#pragma unroll
      for (int ni = 0; ni < 4; ++ni)
        acc[mi][ni] = __builtin_amdgcn_mfma_f32_16x16x32_bf16(af[mi], bfr[ni], acc[mi][ni], 0, 0, 0);
  }

  // Epilogue. D layout: lane l reg j -> row 4*(l>>4)+j, col l&15 (m89-verified).
#pragma unroll
  for (int mi = 0; mi < 4; ++mi)
#pragma unroll
    for (int ni = 0; ni < 4; ++ni) {
      const int nn = n0 + wc * 64 + ni * 16 + cl;
      const float bv = bias[nn];
#pragma unroll
      for (int j = 0; j < 4; ++j) {
        const int mm = m0 + wr * 64 + mi * 16 + 4 * g + j;
        float v = acc[mi][ni][j] + bv;
        if (MODE == 0) {
          v *= scale;
          const int b = mm >> 11, s = mm & (SEQ - 1);
          const int h = nn >> 6, d = nn & 63;
          ((unsigned short*)Cout)[(((size_t)(b * NHEAD + h) * SEQ) + s) * DK + d] = f2bf(v);
        } else if (MODE == 1) {
          const int b = mm >> 11, s = mm & (SEQ - 1);
          const int h = nn >> 6, d = nn & 63;
          ((unsigned short*)Cout)[(((size_t)(b * NHEAD + h) * DK) + d) * SEQ + s] = f2bf(v);
        } else {
          ((float*)Cout)[(size_t)mm * D_MODEL + nn] = v;
        }
      }
    }
}

// ---------------- Flash attention, bf16 MFMA ----------------
// Q pre-scaled by 0.125*log2(e) -> softmax in base-2.
// 4 independent waves per block (no __syncthreads). Wave owns 32 q-rows.
// K frags + V^T frags loaded straight from global (L1/L2-resident tiles).
// P round-trips through per-wave LDS with XOR swizzle (G4: 128B-stride fix).
__global__ __launch_bounds__(256) void attn_mfma(const unsigned short* __restrict__ Qh,
                                                 const unsigned short* __restrict__ Kh,
                                                 const unsigned short* __restrict__ Vt,
                                                 unsigned short* __restrict__ Ctx) {
  __shared__ unsigned short P_lds[4][32 * 64];  // 4 KB per wave
  const int t = threadIdx.x;
  const int lane = t & 63, w = t >> 6;
  const int g = lane >> 4, cl = lane & 15;
  const int q0 = blockIdx.x * 128 + w * 32;
  const size_t bh = (size_t)(blockIdx.z * NHEAD + blockIdx.y) * SEQ * DK;
  const unsigned short* Qp = Qh + bh + (size_t)q0 * DK;
  const unsigned short* Kp = Kh + bh;
  const unsigned short* Vp = Vt + bh;  // [64 d][2048 s]
  char* Pw = (char*)&P_lds[w][0];      // 32 rows x 128 B

  // Q a-frags in registers: lane l -> Q[q0 + mi*16 + (l&15)][ks*32 + 8*(l>>4)+j]
  bf16x8 qf[2][2];
#pragma unroll
  for (int mi = 0; mi < 2; ++mi)
#pragma unroll
    for (int ks = 0; ks < 2; ++ks)
      qf[mi][ks] = *(const bf16x8*)&Qp[(size_t)(mi * 16 + cl) * DK + ks * 32 + g * 8];

  float mrun[2][4], lrun[2][4];
  f32x4 octx[2][4];
#pragma unroll
  for (int mi = 0; mi < 2; ++mi) {
#pragma unroll
    for (int j = 0; j < 4; ++j) { mrun[mi][j] = -1e30f; lrun[mi][j] = 0.f; }
#pragma unroll
    for (int ng = 0; ng < 4; ++ng) octx[mi][ng] = (f32x4){0.f, 0.f, 0.f, 0.f};
  }

  for (int kt = 0; kt < SEQ / 64; ++kt) {
    const int key0 = kt * 64;
    // K b-frags: lane l -> K[key0 + kg*16 + (l&15)][ks*32 + 8*(l>>4)+j]
    bf16x8 kf[4][2];
#pragma unroll
    for (int kg = 0; kg < 4; ++kg)
#pragma unroll
      for (int ks = 0; ks < 2; ++ks)
        kf[kg][ks] = *(const bf16x8*)&Kp[(size_t)(key0 + kg * 16 + cl) * DK + ks * 32 + g * 8];

    // scores[32 q][64 key], already in log2 domain (Q pre-scaled)
    f32x4 sc[2][4];
#pragma unroll
    for (int mi = 0; mi < 2; ++mi)
#pragma unroll
      for (int kg = 0; kg < 4; ++kg) {
        f32x4 s = (f32x4){0.f, 0.f, 0.f, 0.f};
        s = __builtin_amdgcn_mfma_f32_16x16x32_bf16(qf[mi][0], kf[kg][0], s, 0, 0, 0);
        s = __builtin_amdgcn_mfma_f32_16x16x32_bf16(qf[mi][1], kf[kg][1], s, 0, 0, 0);
        sc[mi][kg] = s;  // lane l reg j: q-row 4*(l>>4)+j (+mi*16), key kg*16+(l&15)
      }

    // online softmax (row-reduce across the 16 lanes sharing a q-row)
#pragma unroll
    for (int mi = 0; mi < 2; ++mi) {
      float pm[4];
#pragma unroll
      for (int j = 0; j < 4; ++j)
        pm[j] = fmaxf(fmaxf(sc[mi][0][j], sc[mi][1][j]), fmaxf(sc[mi][2][j], sc[mi][3][j]));
#pragma unroll
      for (int j = 0; j < 4; ++j) {
#pragma unroll
        for (int msk = 1; msk < 16; msk <<= 1) pm[j] = fmaxf(pm[j], __shfl_xor(pm[j], msk, 64));
        const float mnew = fmaxf(mrun[mi][j], pm[j]);
        const float fsc = exp2f(mrun[mi][j] - mnew);
        mrun[mi][j] = mnew;
        lrun[mi][j] *= fsc;
#pragma unroll
        for (int ng = 0; ng < 4; ++ng) octx[mi][ng][j] *= fsc;
      }
      float rs[4] = {0.f, 0.f, 0.f, 0.f};
#pragma unroll
      for (int kg = 0; kg < 4; ++kg)
#pragma unroll
        for (int j = 0; j < 4; ++j) {
          const float p = exp2f(sc[mi][kg][j] - mrun[mi][j]);
          rs[j] += p;
          const int row = mi * 16 + 4 * g + j;
          const int bcol = ((kg * 16 + cl) * 2) ^ ((row & 7) << 4);  // XOR swizzle
          *(unsigned short*)(Pw + row * 128 + bcol) = f2bf(p);
        }
#pragma unroll
      for (int j = 0; j < 4; ++j) {
#pragma unroll
        for (int msk = 1; msk < 16; msk <<= 1) rs[j] += __shfl_xor(rs[j], msk, 64);
        lrun[mi][j] += rs[j];
      }
    }

    // V^T b-frags: lane l -> Vt[ng*16 + (l&15)][key0 + ks*32 + 8*(l>>4)+j]
    bf16x8 vf[4][2];
#pragma unroll
    for (int ng = 0; ng < 4; ++ng)
#pragma unroll
      for (int ks = 0; ks < 2; ++ks)
        vf[ng][ks] = *(const bf16x8*)&Vp[(size_t)(ng * 16 + cl) * SEQ + key0 + ks * 32 + g * 8];

    // P a-frags back from LDS (swizzled ds_read_b128)
    bf16x8 pa[2][2];
#pragma unroll
    for (int mi = 0; mi < 2; ++mi)
#pragma unroll
      for (int ks = 0; ks < 2; ++ks) {
        const int row = mi * 16 + cl;
        const int bcol = (ks * 64 + g * 16) ^ ((row & 7) << 4);
        pa[mi][ks] = *(const bf16x8*)(Pw + row * 128 + bcol);
      }
#pragma unroll
    for (int mi = 0; mi < 2; ++mi)
#pragma unroll
      for (int ng = 0; ng < 4; ++ng) {
        octx[mi][ng] = __builtin_amdgcn_mfma_f32_16x16x32_bf16(pa[mi][0], vf[ng][0], octx[mi][ng], 0, 0, 0);
        octx[mi][ng] = __builtin_amdgcn_mfma_f32_16x16x32_bf16(pa[mi][1], vf[ng][1], octx[mi][ng], 0, 0, 0);
      }
  }

  // Epilogue: ctx bf16, layout [b*2048+s][h*64+d]
#pragma unroll
  for (int mi = 0; mi < 2; ++mi) {
    float inv[4];
#pragma unroll
    for (int j = 0; j < 4; ++j) inv[j] = 1.f / lrun[mi][j];
#pragma unroll
    for (int ng = 0; ng < 4; ++ng)
#pragma unroll
      for (int j = 0; j < 4; ++j) {
        const int q = q0 + mi * 16 + 4 * g + j;
        const int d = ng * 16 + cl;
        Ctx[((size_t)blockIdx.z * SEQ + q) * D_MODEL + blockIdx.y * DK + d] =
            f2bf(octx[mi][ng][j] * inv[j]);
      }
  }
}

extern "C" void kernel_launch(void* const* d_in, const int* in_sizes, int n_in,
                              void* d_out, int out_size, void* d_ws, size_t ws_size,
                              hipStream_t stream) {
  const float* query = (const float*)d_in[0];
  const float* key   = (const float*)d_in[1];
  const float* value = (const float*)d_in[2];
  const float* wq = (const float*)d_in[3];
  const float* bq = (const float*)d_in[4];
  const float* wk = (const float*)d_in[5];
  const float* bk = (const float*)d_in[6];
  const float* wv = (const float*)d_in[7];
  const float* bv = (const float*)d_in[8];
  const float* wo = (const float*)d_in[9];
  const float* bo = (const float*)d_in[10];

  unsigned short* ws = (unsigned short*)d_ws;
  const size_t TA = (size_t)MROWS * D_MODEL;    // 8.39M elems
  const size_t TW = (size_t)D_MODEL * D_MODEL;  // 1.05M elems
  unsigned short* qb  = ws;            // bf16 activations
  unsigned short* kb  = qb + TA;
  unsigned short* vb  = kb + TA;
  unsigned short* wqb = vb + TA;       // bf16 weights
  unsigned short* wkb = wqb + TW;
  unsigned short* wvb = wkb + TW;
  unsigned short* wob = wvb + TW;
  unsigned short* Qh  = wob + TW;      // [B,H,S,64] scaled
  unsigned short* Kh  = Qh + TA;       // [B,H,S,64]
  unsigned short* Vh  = Kh + TA;       // [B,H,64,S]
  unsigned short* Cb  = Vh + TA;       // ctx bf16 [M,1024]
  // total: (7*TA + 4*TW)*2B ~= 125.8 MB of ws

  cvt_bf16<<<dim3((int)(TA / 8 / 256)), 256, 0, stream>>>(query, qb, (int)(TA / 8));
  cvt_bf16<<<dim3((int)(TA / 8 / 256)), 256, 0, stream>>>(key,   kb, (int)(TA / 8));
  cvt_bf16<<<dim3((int)(TA / 8 / 256)), 256, 0, stream>>>(value, vb, (int)(TA / 8));
  cvt_bf16<<<dim3((int)(TW / 8 / 256)), 256, 0, stream>>>(wq, wqb, (int)(TW / 8));
  cvt_bf16<<<dim3((int)(TW / 8 / 256)), 256, 0, stream>>>(wk, wkb, (int)(TW / 8));
  cvt_bf16<<<dim3((int)(TW / 8 / 256)), 256, 0, stream>>>(wv, wvb, (int)(TW / 8));
  cvt_bf16<<<dim3((int)(TW / 8 / 256)), 256, 0, stream>>>(wo, wob, (int)(TW / 8));

  const dim3 gg(D_MODEL / 128, MROWS / 128);  // (8, 64)
  const float s0 = 0.125f * 1.4426950408889634f;  // fold 1/sqrt(dk) * log2(e) into Q
  gemm_bt<0><<<gg, 256, 0, stream>>>(qb, wqb, bq, Qh, s0);
  gemm_bt<0><<<gg, 256, 0, stream>>>(kb, wkb, bk, Kh, 1.0f);
  gemm_bt<1><<<gg, 256, 0, stream>>>(vb, wvb, bv, Vh, 1.0f);

  attn_mfma<<<dim3(SEQ / 128, NHEAD, BATCH), 256, 0, stream>>>(Qh, Kh, Vh, Cb);

  gemm_bt<2><<<gg, 256, 0, stream>>>(Cb, wob, bo, d_out, 1.0f);
}